// Round 10
// baseline (873.793 us; speedup 1.0000x reference)
//
#include <hip/hip_runtime.h>
#include <cmath>

#define B 64
#define S 400
#define V 50000
#define OOV 100
#define H2 1024
#define VDN (V + OOV)   // 50100
#define NBLK_V 782      // ceil(V/64)

typedef __attribute__((ext_vector_type(8))) short short8;
typedef __attribute__((ext_vector_type(4))) float f32x4;

__device__ __forceinline__ float wred_sum(float v) {
#pragma unroll
  for (int o = 32; o > 0; o >>= 1) v += __shfl_down(v, o, 64);
  return v;
}
__device__ __forceinline__ float wred_max(float v) {
#pragma unroll
  for (int o = 32; o > 0; o >>= 1) v = fmaxf(v, __shfl_down(v, o, 64));
  return v;
}
__device__ __forceinline__ short f2bf(float f) {
  return __builtin_bit_cast(short, (__bf16)f);
}
__device__ __forceinline__ float ftanh(float x) {
  float e = __expf(2.f * x);
  return 1.f - 2.f * __builtin_amdgcn_rcpf(e + 1.f);
}
__device__ __forceinline__ float fsig(float x) {
  return __builtin_amdgcn_rcpf(1.f + __expf(-x));
}

// grid barrier: release add -> RELAXED poll (no invalidate storm) -> one acquire
__device__ __forceinline__ void gbar(unsigned* cnt, int slot, unsigned nblk) {
  __syncthreads();
  if (threadIdx.x == 0 && threadIdx.y == 0) {
    __threadfence();
    __hip_atomic_fetch_add(cnt + slot * 32, 1u, __ATOMIC_RELEASE,
                           __HIP_MEMORY_SCOPE_AGENT);
    while (__hip_atomic_load(cnt + slot * 32, __ATOMIC_RELAXED,
                             __HIP_MEMORY_SCOPE_AGENT) < nblk)
      __builtin_amdgcn_s_sleep(8);
    (void)__hip_atomic_load(cnt + slot * 32, __ATOMIC_ACQUIRE,
                            __HIP_MEMORY_SCOPE_AGENT);
  }
  __syncthreads();
}

// ---- zero barrier counters + vd OOV tail ----
__global__ __launch_bounds__(256) void k_zero(unsigned* __restrict__ cnt,
                                              float* __restrict__ vd) {
  int t = blockIdx.x * 256 + threadIdx.x;
  if (t < 2048) cnt[t] = 0u;
  if (t < B * OOV) {
    int b = t / OOV, v = t % OOV;
    vd[(size_t)b * VDN + V + v] = 0.f;
  }
}

// ---- one skinny-GEMM unit: 64 k4-steps, 2 j-rows, atomic accumulate ----
template <int OM>  // 0: T4 out, 1: row-major out
__device__ __forceinline__ void gemm_u(const float* __restrict__ A,
                                       const float* __restrict__ W, int ldw,
                                       int kc0, int j0, float* __restrict__ out,
                                       int ldout, int lane) {
  float a0 = 0.f, a1 = 0.f;
  const float* ap = A + (size_t)kc0 * 256 + lane * 4;
  const float* w0 = W + (size_t)j0 * ldw + kc0 * 4;
  const float* w1 = w0 + ldw;
#pragma unroll 8
  for (int k4 = 0; k4 < 64; ++k4) {
    float4 av = *(const float4*)(ap + k4 * 256);
    float4 v0 = *(const float4*)(w0 + k4 * 4);
    float4 v1 = *(const float4*)(w1 + k4 * 4);
    a0 += av.x * v0.x + av.y * v0.y + av.z * v0.z + av.w * v0.w;
    a1 += av.x * v1.x + av.y * v1.y + av.z * v1.z + av.w * v1.w;
  }
  if constexpr (OM == 0) {
    atomicAdd(&out[((size_t)(j0 >> 2) * 64 + lane) * 4 + (j0 & 3)], a0);
    atomicAdd(&out[((size_t)((j0 + 1) >> 2) * 64 + lane) * 4 + ((j0 + 1) & 3)], a1);
  } else {
    atomicAdd(&out[(size_t)lane * ldout + j0], a0);
    atomicAdd(&out[(size_t)lane * ldout + j0 + 1], a1);
  }
}

#define NF 512  // k_front / k_mid grid

// ---- persistent front: init/pack -> ctx gemm -> gates gemm -> lstm -> dfeat ----
__global__ __launch_bounds__(256) void k_front(
    const float* __restrict__ b_ctx, const float* __restrict__ b_ih,
    const float* __restrict__ b_hh, const float* __restrict__ b_feat,
    const float* __restrict__ b_o1, const float* __restrict__ context,
    const float* __restrict__ emb, const int* __restrict__ sumin,
    const float* __restrict__ h0, const float* __restrict__ c0,
    const float* __restrict__ W_ctx, const float* __restrict__ W_ih,
    const float* __restrict__ W_hh, const float* __restrict__ W_feat,
    float* __restrict__ ctxoutT4, float* __restrict__ gates,
    float* __restrict__ dfeat, float* __restrict__ innerT4,
    float* __restrict__ catT4, float* __restrict__ h0T4,
    float* __restrict__ hidden, float* __restrict__ hidcatT4,
    unsigned* __restrict__ cnt) {
  const int blk = blockIdx.x, t = threadIdx.x;
  const int lane = t & 63, w = t >> 6;
  // P0: bias-init + input packing (360448 elems)
  for (int idx = blk * 256 + t; idx < 360448; idx += NF * 256) {
    if (idx < 16384) {
      int j = ((idx >> 8) << 2) + (idx & 3);
      ctxoutT4[idx] = b_ctx[j];
    } else if (idx < 147456) {
      int i = idx - 16384;
      gates[i] = b_ih[i & 2047] + b_hh[i & 2047];
    } else if (idx < 212992) {
      int i = idx - 147456;
      dfeat[i] = b_feat[i & 1023];
    } else if (idx < 245760) {
      int i = idx - 212992;
      int j = ((i >> 8) << 2) + (i & 3);
      innerT4[i] = b_o1[j];
    } else if (idx < 327680) {
      int i = idx - 245760;
      int e = i & 3, bb = (i >> 2) & 63, q = i >> 8;
      int k = q * 4 + e;
      catT4[i] = (k < 1024) ? context[bb * 1024 + k]
                            : emb[(size_t)sumin[bb] * 256 + (k - 1024)];
    } else {
      int i = idx - 327680;
      int e = i & 3, bb = (i >> 2) & 63, q = i >> 8;
      h0T4[i] = h0[bb * 512 + q * 4 + e];
    }
  }
  gbar(cnt, 0, NF);
  // P1: ctx_out gemm (160 units = 32 jblk x 5 kchunk)
  for (int u = blk; u < 160; u += NF)
    gemm_u<0>(catT4, W_ctx, 1280, (u / 32) * 64, (u % 32) * 8 + w * 2, ctxoutT4,
              0, lane);
  gbar(cnt, 1, NF);
  // P2: gates gemm (768 units)
  for (int u = blk; u < 768; u += NF) {
    int jb = u & 255, y = u >> 8;
    if (y == 0)
      gemm_u<1>(ctxoutT4, W_ih, 256, 0, jb * 8 + w * 2, gates, 2048, lane);
    else
      gemm_u<1>(h0T4, W_hh, 512, (y - 1) * 64, jb * 8 + w * 2, gates, 2048, lane);
  }
  gbar(cnt, 2, NF);
  // P3: lstm pointwise (32768 elems)
  for (int idx = blk * 256 + t; idx < 32768; idx += NF * 256) {
    int b = idx >> 9, u = idx & 511;
    float gi = gates[(size_t)b * 2048 + u];
    float gf = gates[(size_t)b * 2048 + 512 + u];
    float gg = gates[(size_t)b * 2048 + 1024 + u];
    float go = gates[(size_t)b * 2048 + 1536 + u];
    float c = fsig(gf) * c0[(size_t)b * 512 + u] + fsig(gi) * ftanh(gg);
    float h = fsig(go) * ftanh(c);
    hidden[(size_t)b * H2 + u] = h;
    hidden[(size_t)b * H2 + 512 + u] = c;
    hidcatT4[((u >> 2) * 64 + b) * 4 + (u & 3)] = h;
    int k = 512 + u;
    hidcatT4[((k >> 2) * 64 + b) * 4 + (k & 3)] = c;
  }
  gbar(cnt, 3, NF);
  // P4: dec_feat gemm (512 units)
  for (int u = blk; u < 512; u += NF) {
    int jb = u & 127, y = u >> 7;
    gemm_u<1>(hidcatT4, W_feat, 1024, y * 64, jb * 8 + w * 2, dfeat, 1024, lane);
  }
}

// ---- attention scores: block owns (b, 8 s-rows); invariants in registers ----
__global__ __launch_bounds__(256) void k_e(
    const float* __restrict__ ef, const float* __restrict__ dfeat,
    const float* __restrict__ cov, const float* __restrict__ Wcov,
    const float* __restrict__ bcov, const float* __restrict__ watt,
    const float* __restrict__ batt, float* __restrict__ e_out) {
  const int t = threadIdx.x;
  const int b = blockIdx.x & 63;
  const int q = blockIdx.x >> 6;  // 0..49
  float4 dv = ((const float4*)(dfeat + (size_t)b * H2))[t];
  float4 bc = ((const float4*)bcov)[t];
  float4 wc = ((const float4*)Wcov)[t];
  float4 wa = ((const float4*)watt)[t];
  const float bx = dv.x + bc.x, by = dv.y + bc.y;
  const float bz = dv.z + bc.z, bw = dv.w + bc.w;
  __shared__ float part[8][5];
#pragma unroll
  for (int i = 0; i < 8; ++i) {
    const int s = q * 8 + i;
    const int sb = s * B + b;
    const float cval = cov[sb];
    float4 ev = ((const float4*)(ef + (size_t)sb * H2))[t];
    float sum = ftanh(ev.x + bx + cval * wc.x) * wa.x +
                ftanh(ev.y + by + cval * wc.y) * wa.y +
                ftanh(ev.z + bz + cval * wc.z) * wa.z +
                ftanh(ev.w + bw + cval * wc.w) * wa.w;
    sum = wred_sum(sum);
    if ((t & 63) == 0) part[i][t >> 6] = sum;
  }
  __syncthreads();
  if (t < 8) {
    e_out[(q * 8 + t) * B + b] =
        part[t][0] + part[t][1] + part[t][2] + part[t][3] + batt[0];
  }
}

// ---- persistent mid: softmax -> ctx einsum -> reduce -> pgen+inner -> pack ----
__global__ __launch_bounds__(256) void k_mid(
    const float* __restrict__ e_ws, const float* __restrict__ mask,
    const float* __restrict__ coverage, const float* __restrict__ enc,
    const float* __restrict__ Wpg, const float* __restrict__ bpg,
    const float* __restrict__ W_o1, const float* __restrict__ hidden,
    const float* __restrict__ ctxoutT4, const float* __restrict__ hidcatT4,
    float* __restrict__ a_out, float* __restrict__ cov_out,
    float* __restrict__ part, float* __restrict__ ctx_new,
    float* __restrict__ ctxnewT4, float* __restrict__ pgen,
    float* __restrict__ innerT4, short8* __restrict__ packB,
    unsigned* __restrict__ cnt) {
  const int blk = blockIdx.x, t = threadIdx.x;
  const int lane = t & 63, w = t >> 6;
  __shared__ float red[4];
  // P0: masked softmax over s + coverage (blocks 0..63)
  if (blk < 64) {
    const int b = blk;
    float e1 = e_ws[t * B + b];
    float e2 = (t < S - 256) ? e_ws[(t + 256) * B + b] : -INFINITY;
    float m = wred_max(fmaxf(e1, e2));
    if (lane == 0) red[w] = m;
    __syncthreads();
    float M = fmaxf(fmaxf(red[0], red[1]), fmaxf(red[2], red[3]));
    __syncthreads();
    float x1 = mask[t * B + b] * __expf(e1 - M);
    float x2 = (t < S - 256) ? mask[(t + 256) * B + b] * __expf(e2 - M) : 0.f;
    float zs = wred_sum(x1 + x2);
    if (lane == 0) red[w] = zs;
    __syncthreads();
    float Z = red[0] + red[1] + red[2] + red[3];
    float rZ = 1.f / Z;
    float a1 = x1 * rZ;
    a_out[t * B + b] = a1;
    cov_out[t * B + b] = coverage[t * B + b] + a1;
    if (t < S - 256) {
      float a2 = x2 * rZ;
      a_out[(t + 256) * B + b] = a2;
      cov_out[(t + 256) * B + b] = coverage[(t + 256) * B + b] + a2;
    }
  }
  gbar(cnt, 4, NF);
  // P1: ctx einsum partials (block = (q, b), q<8, 50 s each)
  {
    const int b = blk & 63, q = blk >> 6;
    const int d = t * 4;
    float4 acc = make_float4(0.f, 0.f, 0.f, 0.f);
#pragma unroll 10
    for (int i = 0; i < 50; ++i) {
      int s = q * 50 + i;
      float av = a_out[s * B + b];
      float4 ev = *(const float4*)(enc + ((size_t)b * S + s) * H2 + d);
      acc.x += av * ev.x;
      acc.y += av * ev.y;
      acc.z += av * ev.z;
      acc.w += av * ev.w;
    }
    *(float4*)(part + (size_t)(q * 64 + b) * H2 + d) = acc;
  }
  gbar(cnt, 5, NF);
  // P2: reduce 8 partials -> ctx_new + T4 (blocks 0..255)
  if (blk < 256) {
    int idx = blk * 256 + t;
    float s = 0.f;
#pragma unroll
    for (int c = 0; c < 8; ++c) s += part[(size_t)c * 65536 + idx];
    int b = idx >> 10, d = idx & 1023;
    ctx_new[idx] = s;
    ctxnewT4[((d >> 2) * 64 + b) * 4 + (d & 3)] = s;
  }
  gbar(cnt, 6, NF);
  // P3: pgen (units 0..63) + inner gemm (units 64..447)
  for (int u = blk; u < 448; u += NF) {
    if (u < 64) {
      const int b = u;
      float p = 0.f;
      for (int k = t; k < 2304; k += 256) {
        float v;
        if (k < 1024) v = ctx_new[(size_t)b * H2 + k];
        else if (k < 2048) v = hidden[(size_t)b * H2 + k - 1024];
        else {
          int ko = k - 2048;
          v = ctxoutT4[((ko >> 2) * 64 + b) * 4 + (ko & 3)];
        }
        p += v * Wpg[k];
      }
      p = wred_sum(p);
      if (lane == 0) red[w] = p;
      __syncthreads();
      if (t == 0) {
        float dd = red[0] + red[1] + red[2] + red[3] + bpg[0];
        pgen[b] = fsig(dd);
      }
      __syncthreads();
    } else {
      int v = u - 64;
      int jb = v & 63, y = v >> 6;
      if (y < 2)
        gemm_u<0>(hidcatT4, W_o1, 1536, y * 64, jb * 8 + w * 2, innerT4, 0, lane);
      else
        gemm_u<0>(ctxnewT4, W_o1 + 512, 1536, (y - 2) * 64, jb * 8 + w * 2,
                  innerT4, 0, lane);
    }
  }
  gbar(cnt, 7, NF);
  // P4: pack inner into MFMA B-fragments (blocks 0..15)
  if (blk < 16) {
    int f = blk * 256 + t;
    int l = f & 63, bt = (f >> 6) & 3, ks = f >> 8;
    int b = bt * 16 + (l & 15);
    int kbase = ks * 32 + (l >> 4) * 8;
    float4 q0 = *(const float4*)&innerT4[(size_t)(kbase / 4) * 256 + b * 4];
    float4 q1 = *(const float4*)&innerT4[(size_t)(kbase / 4 + 1) * 256 + b * 4];
    short8 frag;
    frag[0] = f2bf(q0.x); frag[1] = f2bf(q0.y);
    frag[2] = f2bf(q0.z); frag[3] = f2bf(q0.w);
    frag[4] = f2bf(q1.x); frag[5] = f2bf(q1.y);
    frag[6] = f2bf(q1.z); frag[7] = f2bf(q1.w);
    packB[f] = frag;
  }
}

// ---- persistent vocab: logits (LDS-resident) -> M,Z -> vd -> scatter ----
__global__ __launch_bounds__(256) void k_mfma(
    const float* __restrict__ W2, const short8* __restrict__ packB,
    const float* __restrict__ bias, const float* __restrict__ pgen,
    const float* __restrict__ a_out, const int* __restrict__ tex,
    float* __restrict__ mp, float* __restrict__ zp, float* __restrict__ mz,
    float* __restrict__ vd, unsigned* __restrict__ cnt) {
  const int l = threadIdx.x;
  const int w = threadIdx.y;
  const int t = w * 64 + l;
  const int jblk = blockIdx.x * 64;
  __shared__ float tile[64][65];
  // P0: logits tile (never written to HBM) + per-block (m,z)
  {
    const int jv = min(jblk + w * 16 + (l & 15), V - 1);
    const float4* wp4 = (const float4*)(W2 + (size_t)jv * 512 + (l >> 4) * 8);
    f32x4 acc0 = {0.f, 0.f, 0.f, 0.f}, acc1 = acc0, acc2 = acc0, acc3 = acc0;
    float4 cw0 = wp4[0], cw1 = wp4[1];
#pragma unroll
    for (int ks = 0; ks < 16; ++ks) {
      float4 nw0, nw1;
      if (ks < 15) { nw0 = wp4[(ks + 1) * 8]; nw1 = wp4[(ks + 1) * 8 + 1]; }
      short8 af;
      af[0] = f2bf(cw0.x); af[1] = f2bf(cw0.y);
      af[2] = f2bf(cw0.z); af[3] = f2bf(cw0.w);
      af[4] = f2bf(cw1.x); af[5] = f2bf(cw1.y);
      af[6] = f2bf(cw1.z); af[7] = f2bf(cw1.w);
      short8 b0 = packB[(ks * 4 + 0) * 64 + l];
      short8 b1 = packB[(ks * 4 + 1) * 64 + l];
      short8 b2 = packB[(ks * 4 + 2) * 64 + l];
      short8 b3 = packB[(ks * 4 + 3) * 64 + l];
      acc0 = __builtin_amdgcn_mfma_f32_16x16x32_bf16(af, b0, acc0, 0, 0, 0);
      acc1 = __builtin_amdgcn_mfma_f32_16x16x32_bf16(af, b1, acc1, 0, 0, 0);
      acc2 = __builtin_amdgcn_mfma_f32_16x16x32_bf16(af, b2, acc2, 0, 0, 0);
      acc3 = __builtin_amdgcn_mfma_f32_16x16x32_bf16(af, b3, acc3, 0, 0, 0);
      if (ks < 15) { cw0 = nw0; cw1 = nw1; }
    }
    const int rbase = w * 16 + (l >> 4) * 4;
#pragma unroll
    for (int v = 0; v < 4; ++v) {
      int jl = rbase + v;
      int j = jblk + jl;
      float bv = bias[min(j, V - 1)];
      bool valid = (j < V);
      tile[jl][0 * 16 + (l & 15)] = valid ? acc0[v] + bv : -INFINITY;
      tile[jl][1 * 16 + (l & 15)] = valid ? acc1[v] + bv : -INFINITY;
      tile[jl][2 * 16 + (l & 15)] = valid ? acc2[v] + bv : -INFINITY;
      tile[jl][3 * 16 + (l & 15)] = valid ? acc3[v] + bv : -INFINITY;
    }
    __syncthreads();
    if (t < 64) {
      float m = -INFINITY;
#pragma unroll
      for (int jl = 0; jl < 64; ++jl) m = fmaxf(m, tile[jl][t]);
      float z = 0.f;
#pragma unroll
      for (int jl = 0; jl < 64; ++jl) z += __expf(tile[jl][t] - m);
      mp[(size_t)blockIdx.x * 64 + t] = m;
      zp[(size_t)blockIdx.x * 64 + t] = z;
    }
  }
  gbar(cnt, 8, NBLK_V);
  // P1: global M, scale = pgen/Z per b (blocks 0..63)
  if ((int)blockIdx.x < 64) {
    const int b = blockIdx.x;
    __shared__ float red2[4];
    float m = -INFINITY;
    for (int i = t; i < NBLK_V; i += 256) m = fmaxf(m, mp[i * 64 + b]);
    m = wred_max(m);
    if (l == 0) red2[w] = m;
    __syncthreads();
    float M = fmaxf(fmaxf(red2[0], red2[1]), fmaxf(red2[2], red2[3]));
    __syncthreads();
    float z = 0.f;
    for (int i = t; i < NBLK_V; i += 256)
      z += zp[i * 64 + b] * __expf(mp[i * 64 + b] - M);
    z = wred_sum(z);
    if (l == 0) red2[w] = z;
    __syncthreads();
    if (t == 0) {
      mz[b] = M;
      mz[64 + b] = pgen[b] / (red2[0] + red2[1] + red2[2] + red2[3]);
    }
  }
  gbar(cnt, 9, NBLK_V);
  // P2: vd = scale * exp(logit - M), straight from the LDS tile
#pragma unroll
  for (int i = 0; i < 16; ++i) {
    int idx = i * 256 + t;
    int jl = idx & 63;
    int b = idx >> 6;
    int j = jblk + jl;
    if (j < V)
      vd[(size_t)b * VDN + j] = mz[64 + b] * __expf(tile[jl][b] - mz[b]);
  }
  gbar(cnt, 10, NBLK_V);
  // P3: scatter-add copy distribution (blocks 0..99)
  if ((int)blockIdx.x < 100) {
    int g = blockIdx.x * 256 + t;
    if (g < S * B) {
      int b = g & 63;
      float wgt = (1.f - pgen[b]) * a_out[g];
      atomicAdd(&vd[(size_t)b * VDN + tex[g]], wgt);
    }
  }
}

extern "C" void kernel_launch(void* const* d_in, const int* in_sizes, int n_in,
                              void* d_out, int out_size, void* d_ws, size_t ws_size,
                              hipStream_t stream) {
  const int* sumin = (const int*)d_in[0];
  const float* h0 = (const float*)d_in[1];
  const float* c0 = (const float*)d_in[2];
  const float* enc_out = (const float*)d_in[3];
  const float* ef = (const float*)d_in[4];
  const float* mask = (const float*)d_in[5];
  const float* context = (const float*)d_in[6];
  const float* coverage = (const float*)d_in[7];
  const int* tex = (const int*)d_in[8];
  const float* emb = (const float*)d_in[10];
  const float* W_feat = (const float*)d_in[11];
  const float* b_feat = (const float*)d_in[12];
  const float* W_cov = (const float*)d_in[13];
  const float* b_cov = (const float*)d_in[14];
  const float* w_att = (const float*)d_in[15];
  const float* b_att = (const float*)d_in[16];
  const float* W_ih = (const float*)d_in[17];
  const float* W_hh = (const float*)d_in[18];
  const float* b_ih = (const float*)d_in[19];
  const float* b_hh = (const float*)d_in[20];
  const float* W_ctx = (const float*)d_in[21];
  const float* b_ctx = (const float*)d_in[22];
  const float* W_pg = (const float*)d_in[23];
  const float* b_pg = (const float*)d_in[24];
  const float* W_o1 = (const float*)d_in[25];
  const float* b_o1 = (const float*)d_in[26];
  const float* W_o2 = (const float*)d_in[27];
  const float* b_o2 = (const float*)d_in[28];

  float* out = (float*)d_out;
  float* vd = out;                           // [64][50100]
  float* hidden = vd + (size_t)B * VDN;      // [64][1024] = [h|c]
  float* ctx_new = hidden + (size_t)B * H2;  // [64][1024]
  float* a_out = ctx_new + (size_t)B * H2;   // [400][64]
  float* cov_out = a_out + (size_t)S * B;    // [400][64]

  float* ws = (float*)d_ws;
  float* catT4 = ws;                   // 81920
  float* h0T4 = catT4 + 81920;         // 32768
  float* ctxoutT4 = h0T4 + 32768;      // 16384
  float* gates = ctxoutT4 + 16384;     // 131072
  float* hidcatT4 = gates + 131072;    // 65536
  float* dfeat = hidcatT4 + 65536;     // 65536
  float* e_ws = dfeat + 65536;         // 25600
  float* ctxnewT4 = e_ws + 25600;      // 65536
  float* innerT4 = ctxnewT4 + 65536;   // 32768
  float* pgen = innerT4 + 32768;       // 64
  float* mp = pgen + 64;               // 50048
  float* zp = mp + 50048;              // 50048
  float* mz = zp + 50048;              // 128
  float* packBf = mz + 128;            // 16384 floats = 4096 short8
  float* part = packBf + 16384;        // 8*65536 = 524288
  unsigned* cnt = (unsigned*)(part + 524288);  // 2048 u32
  short8* packB = (short8*)packBf;

  k_zero<<<25, 256, 0, stream>>>(cnt, vd);
  k_front<<<NF, 256, 0, stream>>>(b_ctx, b_ih, b_hh, b_feat, b_o1, context,
                                  emb, sumin, h0, c0, W_ctx, W_ih, W_hh,
                                  W_feat, ctxoutT4, gates, dfeat, innerT4,
                                  catT4, h0T4, hidden, hidcatT4, cnt);
  k_e<<<50 * 64, 256, 0, stream>>>(ef, dfeat, coverage, W_cov, b_cov, w_att,
                                   b_att, e_ws);
  k_mid<<<NF, 256, 0, stream>>>(e_ws, mask, coverage, enc_out, W_pg, b_pg,
                                W_o1, hidden, ctxoutT4, hidcatT4, a_out,
                                cov_out, part, ctx_new, ctxnewT4, pgen,
                                innerT4, packB, cnt);
  k_mfma<<<dim3(NBLK_V), dim3(64, 4), 0, stream>>>(W_o2, packB, b_o2, pgen,
                                                   a_out, tex, mp, zp, mz, vd,
                                                   cnt);
}

// Round 11
// 206.451 us; speedup vs baseline: 4.2325x; 4.2325x over previous
//
#include <hip/hip_runtime.h>
#include <cmath>

#define B 64
#define S 400
#define H 512
#define E 256
#define V 50000
#define OOV 100
#define H2 1024
#define VDN (V + OOV)   // 50100
#define NBLK_V 782      // ceil(V/64)
#define SC 8            // ctxp s-chunks (50 s each)

typedef __attribute__((ext_vector_type(8))) short short8;
typedef __attribute__((ext_vector_type(4))) float f32x4;

__device__ __forceinline__ float wred_sum(float v) {
#pragma unroll
  for (int o = 32; o > 0; o >>= 1) v += __shfl_down(v, o, 64);
  return v;
}
__device__ __forceinline__ float wred_max(float v) {
#pragma unroll
  for (int o = 32; o > 0; o >>= 1) v = fmaxf(v, __shfl_down(v, o, 64));
  return v;
}
__device__ __forceinline__ short f2bf(float f) {
  return __builtin_bit_cast(short, (__bf16)f);
}
__device__ __forceinline__ float ftanh(float x) {
  float e = __expf(2.f * x);
  return 1.f - 2.f * __builtin_amdgcn_rcpf(e + 1.f);
}
__device__ __forceinline__ float fsig(float x) {
  return __builtin_amdgcn_rcpf(1.f + __expf(-x));
}

// ---- fused: bias-init GEMM outputs + pack catT4/h0T4 ----
__global__ __launch_bounds__(256) void k_pre(
    const float* __restrict__ b_ctx, const float* __restrict__ b_ih,
    const float* __restrict__ b_hh, const float* __restrict__ b_feat,
    const float* __restrict__ b_o1, const float* __restrict__ context,
    const float* __restrict__ emb, const int* __restrict__ sumin,
    const float* __restrict__ h0, float* __restrict__ ctxoutT4,
    float* __restrict__ gates, float* __restrict__ dfeat,
    float* __restrict__ innerT4, float* __restrict__ catT4,
    float* __restrict__ h0T4) {
  int idx = blockIdx.x * 256 + threadIdx.x;  // < 360448
  if (idx < 16384) {
    int j = ((idx >> 8) << 2) + (idx & 3);
    ctxoutT4[idx] = b_ctx[j];
  } else if (idx < 16384 + 131072) {
    int i = idx - 16384;
    int j = i & 2047;
    gates[i] = b_ih[j] + b_hh[j];
  } else if (idx < 16384 + 131072 + 65536) {
    int i = idx - 16384 - 131072;
    dfeat[i] = b_feat[i & 1023];
  } else if (idx < 245760) {
    int i = idx - 16384 - 131072 - 65536;
    int j = ((i >> 8) << 2) + (i & 3);
    innerT4[i] = b_o1[j];
  } else if (idx < 245760 + 81920) {
    int i = idx - 245760;
    int e = i & 3, b = (i >> 2) & 63, q = i >> 8;
    int k = q * 4 + e;
    catT4[i] = (k < 1024) ? context[b * 1024 + k]
                          : emb[(size_t)sumin[b] * 256 + (k - 1024)];
  } else {
    int i = idx - 245760 - 81920;  // < 32768
    int e = i & 3, b = (i >> 2) & 63, q = i >> 8;
    h0T4[i] = h0[b * 512 + q * 4 + e];
  }
}

// ---- split-K skinny GEMM, atomic accumulate into bias-initialized out ----
template <int R, int KC, int OUTMODE>
__global__ __launch_bounds__(256) void k_gemmsk(
    const float* __restrict__ A1, const float* __restrict__ W1, int ldw1, int s1,
    const float* __restrict__ A2, const float* __restrict__ W2, int ldw2,
    float* __restrict__ out, int ldout) {
  const int lane = threadIdx.x;
  const int w = threadIdx.y;
  const int j0 = blockIdx.x * (4 * R) + w * R;
  const float* A;
  const float* W;
  int ldw, kc0;
  if ((int)blockIdx.y < s1) {
    A = A1; W = W1; ldw = ldw1; kc0 = blockIdx.y * KC;
  } else {
    A = A2; W = W2; ldw = ldw2; kc0 = (blockIdx.y - s1) * KC;
  }
  float acc[R];
#pragma unroll
  for (int r = 0; r < R; ++r) acc[r] = 0.f;
  const float* ap = A + (size_t)kc0 * 256 + lane * 4;
  const float* wr[R];
#pragma unroll
  for (int r = 0; r < R; ++r) wr[r] = W + (size_t)(j0 + r) * ldw + kc0 * 4;
#pragma unroll 8
  for (int k4 = 0; k4 < KC; ++k4) {
    float4 av = *(const float4*)(ap + (size_t)k4 * 256);
#pragma unroll
    for (int r = 0; r < R; ++r) {
      float4 wv = *(const float4*)(wr[r] + k4 * 4);
      acc[r] += av.x * wv.x + av.y * wv.y + av.z * wv.z + av.w * wv.w;
    }
  }
#pragma unroll
  for (int r = 0; r < R; ++r) {
    int j = j0 + r;
    if constexpr (OUTMODE == 0)
      atomicAdd(&out[((size_t)(j >> 2) * 64 + lane) * 4 + (j & 3)], acc[r]);
    else
      atomicAdd(&out[(size_t)lane * ldout + j], acc[r]);
  }
}

// ---- LSTM pointwise: hidden=[h|c] row-major (d_out) + hidcat T4 ----
__global__ __launch_bounds__(256) void k_lstm(const float* __restrict__ gates,
                                              const float* __restrict__ c0,
                                              float* __restrict__ hidden,
                                              float* __restrict__ hcT4) {
  int idx = blockIdx.x * 256 + threadIdx.x;  // 32768
  int b = idx >> 9, u = idx & 511;
  float gi = gates[(size_t)b * 2048 + u];
  float gf = gates[(size_t)b * 2048 + 512 + u];
  float gg = gates[(size_t)b * 2048 + 1024 + u];
  float go = gates[(size_t)b * 2048 + 1536 + u];
  float c = fsig(gf) * c0[(size_t)b * 512 + u] + fsig(gi) * ftanh(gg);
  float h = fsig(go) * ftanh(c);
  hidden[(size_t)b * H2 + u] = h;
  hidden[(size_t)b * H2 + 512 + u] = c;
  hcT4[((u >> 2) * 64 + b) * 4 + (u & 3)] = h;
  int k = 512 + u;
  hcT4[((k >> 2) * 64 + b) * 4 + (k & 3)] = c;
}

// ---- attention scores: block owns (b, 8 s-rows); invariants in registers ----
__global__ __launch_bounds__(256) void k_e(
    const float* __restrict__ ef, const float* __restrict__ dfeat,
    const float* __restrict__ cov, const float* __restrict__ Wcov,
    const float* __restrict__ bcov, const float* __restrict__ watt,
    const float* __restrict__ batt, float* __restrict__ e_out) {
  const int t = threadIdx.x;
  const int b = blockIdx.x & 63;
  const int q = blockIdx.x >> 6;  // 0..49
  float4 dv = ((const float4*)(dfeat + (size_t)b * H2))[t];
  float4 bc = ((const float4*)bcov)[t];
  float4 wc = ((const float4*)Wcov)[t];
  float4 wa = ((const float4*)watt)[t];
  const float bx = dv.x + bc.x, by = dv.y + bc.y;
  const float bz = dv.z + bc.z, bw = dv.w + bc.w;
  __shared__ float part[8][5];
#pragma unroll
  for (int i = 0; i < 8; ++i) {
    const int s = q * 8 + i;
    const int sb = s * B + b;
    const float cval = cov[sb];
    float4 ev = ((const float4*)(ef + (size_t)sb * H2))[t];
    float sum = ftanh(ev.x + bx + cval * wc.x) * wa.x +
                ftanh(ev.y + by + cval * wc.y) * wa.y +
                ftanh(ev.z + bz + cval * wc.z) * wa.z +
                ftanh(ev.w + bw + cval * wc.w) * wa.w;
    sum = wred_sum(sum);
    if ((t & 63) == 0) part[i][t >> 6] = sum;
  }
  __syncthreads();
  if (t < 8) {
    e_out[(q * 8 + t) * B + b] =
        part[t][0] + part[t][1] + part[t][2] + part[t][3] + batt[0];
  }
}

// ---- fused masked softmax (redundant per block) + ctx einsum chunk ----
// grid: sc*64+b, sc<8. Each block: full softmax stats, then its 50-s chunk.
__global__ __launch_bounds__(256) void k_softctx(
    const float* __restrict__ e_ws, const float* __restrict__ mask,
    const float* __restrict__ coverage, const float* __restrict__ enc,
    float* __restrict__ a_out, float* __restrict__ cov_out,
    float* __restrict__ part) {
  const int b = blockIdx.x & 63;
  const int sc = blockIdx.x >> 6;
  const int t = threadIdx.x;
  const int lane = t & 63, w = t >> 6;
  __shared__ float red[4];
  __shared__ float aS[50];
  // softmax stats over full S (thread t covers s=t and s=t+256)
  float e1 = e_ws[t * B + b];
  float e2 = (t < S - 256) ? e_ws[(t + 256) * B + b] : -INFINITY;
  float m = wred_max(fmaxf(e1, e2));
  if (lane == 0) red[w] = m;
  __syncthreads();
  const float M = fmaxf(fmaxf(red[0], red[1]), fmaxf(red[2], red[3]));
  __syncthreads();
  float x1 = mask[t * B + b] * __expf(e1 - M);
  float x2 = (t < S - 256) ? mask[(t + 256) * B + b] * __expf(e2 - M) : 0.f;
  float zs = wred_sum(x1 + x2);
  if (lane == 0) red[w] = zs;
  __syncthreads();
  const float Z = red[0] + red[1] + red[2] + red[3];
  const float rZ = 1.f / Z;
  // my 50 a-values -> LDS + outputs (exclusive s-range per block)
  if (t < 50) {
    int s = sc * 50 + t;
    float ex = mask[s * B + b] * __expf(e_ws[s * B + b] - M);
    float av = ex * rZ;
    aS[t] = av;
    a_out[s * B + b] = av;
    cov_out[s * B + b] = coverage[s * B + b] + av;
  }
  __syncthreads();
  // ctx chunk: thread t owns d = t*4
  const int d = t * 4;
  float4 acc = make_float4(0.f, 0.f, 0.f, 0.f);
#pragma unroll 10
  for (int i = 0; i < 50; ++i) {
    int s = sc * 50 + i;
    float av = aS[i];
    float4 ev = *(const float4*)(enc + ((size_t)b * S + s) * H2 + d);
    acc.x += av * ev.x;
    acc.y += av * ev.y;
    acc.z += av * ev.z;
    acc.w += av * ev.w;
  }
  *(float4*)(part + (size_t)blockIdx.x * H2 + d) = acc;
}

// ---- fused: reduce 8 ctx partials -> ctx_new/T4 + p_gen (block = b) ----
__global__ __launch_bounds__(256) void k_ctxpg(
    const float* __restrict__ part, const float* __restrict__ hidden,
    const float* __restrict__ ctxoutT4, const float* __restrict__ Wpg,
    const float* __restrict__ bpg, float* __restrict__ ctx_new,
    float* __restrict__ ctxT4, float* __restrict__ pgen) {
  const int b = blockIdx.x;
  const int t = threadIdx.x;
  const int lane = t & 63, w = t >> 6;
  const int d = t * 4;
  float4 s = make_float4(0.f, 0.f, 0.f, 0.f);
#pragma unroll
  for (int sc = 0; sc < SC; ++sc) {
    float4 v = *(const float4*)(part + (size_t)(sc * 64 + b) * H2 + d);
    s.x += v.x; s.y += v.y; s.z += v.z; s.w += v.w;
  }
  *(float4*)(ctx_new + (size_t)b * H2 + d) = s;
  *(float4*)(ctxT4 + (size_t)t * 256 + b * 4) = s;
  // p_gen dot: ctx part from registers; hidden + ctxout parts strided
  float p = s.x * Wpg[d] + s.y * Wpg[d + 1] + s.z * Wpg[d + 2] + s.w * Wpg[d + 3];
#pragma unroll
  for (int j = 0; j < 4; ++j) {
    int k = t + j * 256;
    p += hidden[(size_t)b * H2 + k] * Wpg[1024 + k];
  }
  p += ctxoutT4[(size_t)(t >> 2) * 256 + b * 4 + (t & 3)] * Wpg[2048 + t];
  p = wred_sum(p);
  __shared__ float red[4];
  if (lane == 0) red[w] = p;
  __syncthreads();
  if (t == 0) {
    float dd = red[0] + red[1] + red[2] + red[3] + bpg[0];
    pgen[b] = fsig(dd);
  }
}

// ---- pack inner into MFMA B-fragments ----
__global__ __launch_bounds__(256) void k_packinner(const float* __restrict__ innerT4,
                                                   short8* __restrict__ packB) {
  int f = blockIdx.x * 256 + threadIdx.x;  // < 4096
  int l = f & 63, bt = (f >> 6) & 3, ks = f >> 8;
  int b = bt * 16 + (l & 15);
  int kbase = ks * 32 + (l >> 4) * 8;
  float4 q0 = *(const float4*)&innerT4[(size_t)(kbase / 4) * 256 + b * 4];
  float4 q1 = *(const float4*)&innerT4[(size_t)(kbase / 4 + 1) * 256 + b * 4];
  short8 frag;
  frag[0] = f2bf(q0.x); frag[1] = f2bf(q0.y);
  frag[2] = f2bf(q0.z); frag[3] = f2bf(q0.w);
  frag[4] = f2bf(q1.x); frag[5] = f2bf(q1.y);
  frag[6] = f2bf(q1.z); frag[7] = f2bf(q1.w);
  packB[f] = frag;
}

// ---- logits via bf16 MFMA, pipelined W loads, fused softmax partials ----
__global__ __launch_bounds__(256) void k_mfma_logits(
    const float* __restrict__ W2, const short8* __restrict__ packB,
    const float* __restrict__ bias, float* __restrict__ logits,
    float* __restrict__ mp, float* __restrict__ zp) {
  const int l = threadIdx.x;
  const int w = threadIdx.y;
  const int jblk = blockIdx.x * 64;
  const int jv = min(jblk + w * 16 + (l & 15), V - 1);
  const float4* wp4 = (const float4*)(W2 + (size_t)jv * 512 + (l >> 4) * 8);

  f32x4 acc0 = {0.f, 0.f, 0.f, 0.f}, acc1 = acc0, acc2 = acc0, acc3 = acc0;
  float4 cw0 = wp4[0], cw1 = wp4[1];
#pragma unroll
  for (int ks = 0; ks < 16; ++ks) {
    float4 nw0, nw1;
    if (ks < 15) { nw0 = wp4[(ks + 1) * 8]; nw1 = wp4[(ks + 1) * 8 + 1]; }
    short8 af;
    af[0] = f2bf(cw0.x); af[1] = f2bf(cw0.y); af[2] = f2bf(cw0.z); af[3] = f2bf(cw0.w);
    af[4] = f2bf(cw1.x); af[5] = f2bf(cw1.y); af[6] = f2bf(cw1.z); af[7] = f2bf(cw1.w);
    short8 b0 = packB[(ks * 4 + 0) * 64 + l];
    short8 b1 = packB[(ks * 4 + 1) * 64 + l];
    short8 b2 = packB[(ks * 4 + 2) * 64 + l];
    short8 b3 = packB[(ks * 4 + 3) * 64 + l];
    acc0 = __builtin_amdgcn_mfma_f32_16x16x32_bf16(af, b0, acc0, 0, 0, 0);
    acc1 = __builtin_amdgcn_mfma_f32_16x16x32_bf16(af, b1, acc1, 0, 0, 0);
    acc2 = __builtin_amdgcn_mfma_f32_16x16x32_bf16(af, b2, acc2, 0, 0, 0);
    acc3 = __builtin_amdgcn_mfma_f32_16x16x32_bf16(af, b3, acc3, 0, 0, 0);
    if (ks < 15) { cw0 = nw0; cw1 = nw1; }
  }

  __shared__ float tile[64][65];
  const int rbase = w * 16 + (l >> 4) * 4;
#pragma unroll
  for (int v = 0; v < 4; ++v) {
    int jl = rbase + v;
    int j = jblk + jl;
    float bv = bias[min(j, V - 1)];
    bool valid = (j < V);
    tile[jl][0 * 16 + (l & 15)] = valid ? acc0[v] + bv : -INFINITY;
    tile[jl][1 * 16 + (l & 15)] = valid ? acc1[v] + bv : -INFINITY;
    tile[jl][2 * 16 + (l & 15)] = valid ? acc2[v] + bv : -INFINITY;
    tile[jl][3 * 16 + (l & 15)] = valid ? acc3[v] + bv : -INFINITY;
  }
  __syncthreads();
  const int t = w * 64 + l;
#pragma unroll
  for (int i = 0; i < 16; ++i) {
    int idx = i * 256 + t;
    int jl = idx & 63;
    int b = idx >> 6;
    int j = jblk + jl;
    if (j < V) logits[(size_t)b * V + j] = tile[jl][b];
  }
  if (t < 64) {
    float m = -INFINITY;
#pragma unroll
    for (int jl = 0; jl < 64; ++jl) m = fmaxf(m, tile[jl][t]);
    float z = 0.f;
#pragma unroll
    for (int jl = 0; jl < 64; ++jl) z += __expf(tile[jl][t] - m);
    mp[(size_t)blockIdx.x * 64 + t] = m;
    zp[(size_t)blockIdx.x * 64 + t] = z;
  }
}

// ---- fused: (M,Z) reduce + vd = p_gen*softmax + LDS-hist scatter ----
// grid: b*8+c; block handles v-range [c*6272, min(+6272, VDN)) of row b.
__global__ __launch_bounds__(256) void k_vdms(
    const float* __restrict__ logits, const float* __restrict__ mp,
    const float* __restrict__ zp, const float* __restrict__ pgen,
    const float* __restrict__ a_out, const int* __restrict__ tex,
    float* __restrict__ out) {
  const int b = blockIdx.x >> 3;
  const int c = blockIdx.x & 7;
  const int t = threadIdx.x;
  const int lane = t & 63, w = t >> 6;
  __shared__ float red[4];
  __shared__ float hist[6272];
  float m = -INFINITY;
  for (int i = t; i < NBLK_V; i += 256) m = fmaxf(m, mp[i * 64 + b]);
  m = wred_max(m);
  if (lane == 0) red[w] = m;
  __syncthreads();
  const float M = fmaxf(fmaxf(red[0], red[1]), fmaxf(red[2], red[3]));
  __syncthreads();
  float z = 0.f;
  for (int i = t; i < NBLK_V; i += 256) z += zp[i * 64 + b] * __expf(mp[i * 64 + b] - M);
  z = wred_sum(z);
  if (lane == 0) red[w] = z;
  __syncthreads();
  const float Z = red[0] + red[1] + red[2] + red[3];
  const float pg = pgen[b];
  const float scale = pg / Z;
  const float wq = 1.f - pg;
  const int v0 = c * 6272;
  const int v1 = min(v0 + 6272, VDN);
  for (int i = t; i < 6272; i += 256) hist[i] = 0.f;
  __syncthreads();
  for (int s = t; s < S; s += 256) {
    int v = tex[s * B + b];
    if (v >= v0 && v < v1) atomicAdd(&hist[v - v0], wq * a_out[s * B + b]);
  }
  __syncthreads();
  for (int v = v0 + t; v < v1; v += 256) {
    float val = (v < V) ? scale * __expf(logits[(size_t)b * V + v] - M) : 0.f;
    out[(size_t)b * VDN + v] = val + hist[v - v0];
  }
}

extern "C" void kernel_launch(void* const* d_in, const int* in_sizes, int n_in,
                              void* d_out, int out_size, void* d_ws, size_t ws_size,
                              hipStream_t stream) {
  const int* sumin = (const int*)d_in[0];
  const float* h0 = (const float*)d_in[1];
  const float* c0 = (const float*)d_in[2];
  const float* enc_out = (const float*)d_in[3];
  const float* ef = (const float*)d_in[4];
  const float* mask = (const float*)d_in[5];
  const float* context = (const float*)d_in[6];
  const float* coverage = (const float*)d_in[7];
  const int* tex = (const int*)d_in[8];
  const float* emb = (const float*)d_in[10];
  const float* W_feat = (const float*)d_in[11];
  const float* b_feat = (const float*)d_in[12];
  const float* W_cov = (const float*)d_in[13];
  const float* b_cov = (const float*)d_in[14];
  const float* w_att = (const float*)d_in[15];
  const float* b_att = (const float*)d_in[16];
  const float* W_ih = (const float*)d_in[17];
  const float* W_hh = (const float*)d_in[18];
  const float* b_ih = (const float*)d_in[19];
  const float* b_hh = (const float*)d_in[20];
  const float* W_ctx = (const float*)d_in[21];
  const float* b_ctx = (const float*)d_in[22];
  const float* W_pg = (const float*)d_in[23];
  const float* b_pg = (const float*)d_in[24];
  const float* W_o1 = (const float*)d_in[25];
  const float* b_o1 = (const float*)d_in[26];
  const float* W_o2 = (const float*)d_in[27];
  const float* b_o2 = (const float*)d_in[28];

  float* out = (float*)d_out;
  float* vd = out;                           // [64][50100]
  float* hidden = vd + (size_t)B * VDN;      // [64][1024] = [h|c]
  float* ctx_new = hidden + (size_t)B * H2;  // [64][1024]
  float* a_out = ctx_new + (size_t)B * H2;   // [400][64]
  float* cov_out = a_out + (size_t)S * B;    // [400][64]

  float* ws = (float*)d_ws;
  float* catT4 = ws;                   // 81920
  float* h0T4 = catT4 + 81920;         // 32768
  float* ctxoutT4 = h0T4 + 32768;      // 16384
  float* gates = ctxoutT4 + 16384;     // 131072
  float* hidcatT4 = gates + 131072;    // 65536
  float* dfeat = hidcatT4 + 65536;     // 65536
  float* e_ws = dfeat + 65536;         // 25600
  float* ctxnewT4 = e_ws + 25600;      // 65536
  float* innerT4 = ctxnewT4 + 65536;   // 32768
  float* pgen = innerT4 + 32768;       // 64
  float* mp = pgen + 64;               // 50048
  float* zp = mp + 50048;              // 50048
  float* packBf = zp + 50048;          // 16384 floats = 4096 short8
  float* logits = packBf + 16384;      // 3200000
  float* part = logits;                // alias: SC*65536 = 524288 <= 3200000
  short8* packB = (short8*)packBf;

  dim3 gblk(64, 4);

  k_pre<<<1408, 256, 0, stream>>>(b_ctx, b_ih, b_hh, b_feat, b_o1, context, emb,
                                  sumin, h0, ctxoutT4, gates, dfeat, innerT4,
                                  catT4, h0T4);
  // ctx_out += [context|x] @ W_ctx.T   (T4 out)
  k_gemmsk<2, 64, 0><<<dim3(32, 5), gblk, 0, stream>>>(
      catT4, W_ctx, 1280, 5, nullptr, nullptr, 0, ctxoutT4, 0);
  // gates += ctx_out@W_ih.T  and  h0@W_hh.T   (row-major out)
  k_gemmsk<2, 64, 1><<<dim3(256, 3), gblk, 0, stream>>>(
      ctxoutT4, W_ih, 256, 1, h0T4, W_hh, 512, gates, 2048);
  k_lstm<<<128, 256, 0, stream>>>(gates, c0, hidden, hidcatT4);
  // dec_feat += hidden @ W_feat.T   (row-major out)
  k_gemmsk<2, 64, 1><<<dim3(128, 4), gblk, 0, stream>>>(
      hidcatT4, W_feat, 1024, 4, nullptr, nullptr, 0, dfeat, 1024);
  k_e<<<50 * 64, 256, 0, stream>>>(ef, dfeat, coverage, W_cov, b_cov, w_att,
                                   b_att, e_ws);
  // fused softmax + ctx einsum chunks (writes a_out/cov_out outputs too)
  k_softctx<<<SC * B, 256, 0, stream>>>(e_ws, mask, coverage, enc_out, a_out,
                                        cov_out, part);
  // fused ctx reduce + p_gen
  k_ctxpg<<<B, 256, 0, stream>>>(part, hidden, ctxoutT4, W_pg, b_pg, ctx_new,
                                 ctxnewT4, pgen);
  // inner += h@W_o1[:, :512].T  and  ctx_new@W_o1[:, 512:].T   (T4 out)
  k_gemmsk<2, 64, 0><<<dim3(64, 6), gblk, 0, stream>>>(
      hidcatT4, W_o1, 1536, 2, ctxnewT4, W_o1 + 512, 1536, innerT4, 0);
  k_packinner<<<16, 256, 0, stream>>>(innerT4, packB);
  k_mfma_logits<<<NBLK_V, gblk, 0, stream>>>(W_o2, packB, b_o2, logits, mp, zp);
  // fused (M,Z) + vd write + LDS-hist scatter
  k_vdms<<<B * 8, 256, 0, stream>>>(logits, mp, zp, pgen, a_out, tex, vd);
}